// Round 4
// baseline (1905.878 us; speedup 1.0000x reference)
//
#include <hip/hip_runtime.h>
#include <math.h>

#define NB 32
#define LQ 784
#define LQP 832   // 13*64, padded sequence length for attention buffers
#define DIM 512
#define HEADS 8
#define MLP 2048
#define KPAD 448
#define MROWS 25088  // NB*LQ

typedef __attribute__((ext_vector_type(8))) short s8v;
typedef __attribute__((ext_vector_type(4))) short s4v;
typedef __attribute__((ext_vector_type(4))) float f4v;

__device__ __forceinline__ short f2b(float f){
  unsigned u = __builtin_bit_cast(unsigned, f);
  u = (u + 0x7fffu + ((u >> 16) & 1u)) >> 16;
  return (short)u;
}
__device__ __forceinline__ float b2f(short s){
  unsigned u = ((unsigned)(unsigned short)s) << 16;
  return __builtin_bit_cast(float, u);
}

// async global->LDS, 16B per lane. LDS dest pattern must be wave-uniform base + lane*16.
__device__ __forceinline__ void gll16(const short* g, short* l){
  __builtin_amdgcn_global_load_lds(
      (const __attribute__((address_space(1))) void*)g,
      (__attribute__((address_space(3))) void*)l, 16, 0, 0);
}

// ---------------- fused mask prep (single block) ----------------
__global__ __launch_bounds__(512) void mask_k(const int* __restrict__ done, float* __restrict__ keepL,
                                              int* __restrict__ kmask, int* __restrict__ liveg){
  __shared__ float keep[32][16];
  int tid = threadIdx.x;
  { int n = tid >> 4, t = tid & 15;
    int any = 0;
    for (int c = t; c < 15; ++c) any |= done[n*15 + c];
    keep[n][t] = any ? 0.f : 1.f; }
  __syncthreads();
  for (int i = tid; i < NB*LQP; i += 512){
    int n = i / LQP, l = i - n*LQP;
    keepL[i] = (l < LQ) ? keep[n][l/49] : 0.f;
  }
  if (tid < 32){
    int n = tid, m = 0;
    for (int kb = 0; kb < 13; ++kb){
      int t0 = (kb*64)/49, t1 = (kb*64 + 63)/49; if (t1 > 15) t1 = 15;
      float a = 0.f;
      for (int t = t0; t <= t1; ++t) a += keep[n][t];
      if (a > 0.5f) m |= 1 << kb;
    }
    kmask[n] = m;
  }
  for (int g = tid; g < 392; g += 512){
    float a = 0.f;
    for (int i2 = 0; i2 < 64; ++i2){
      int row = g*64 + i2;
      int n = row / 784, l = row - n*784;
      a += keep[n][l/49];
    }
    liveg[g] = a > 0.5f ? 1 : 0;
  }
}

// zero pad rows/cols once, vectorized s8v stores
__global__ __launch_bounds__(256) void zpad_k(short* __restrict__ Qb, short* __restrict__ Kb,
                                              short* __restrict__ Vtb){
  int idx = blockIdx.x*256 + threadIdx.x;   // < 294912
  s8v z;
  #pragma unroll
  for (int e=0;e<8;++e) z[e] = 0;
  if (idx < 98304){
    int nh = idx / 384, r = idx - nh*384;
    *(s8v*)(Qb + (long)nh*LQP*64 + 784*64 + r*8) = z;
  } else if (idx < 196608){
    int i2 = idx - 98304; int nh = i2 / 384, r = i2 - nh*384;
    *(s8v*)(Kb + (long)nh*LQP*64 + 784*64 + r*8) = z;
  } else {
    int i2 = idx - 196608; int nh = i2 / 384, rem = i2 - nh*384, d = rem/6, s = rem - d*6;
    *(s8v*)(Vtb + ((long)nh*64 + d)*LQP + 784 + s*8) = z;
  }
}

// Vm[nh*64+d] = mean over l<784 of V  (V^T layout)
__global__ __launch_bounds__(256) void vmean_k(const short* __restrict__ Vtb, float* __restrict__ Vm){
  int nh = blockIdx.x;
  int tid = threadIdx.x;
  int d = tid >> 2, seg = tid & 3;
  const short* row = Vtb + ((long)nh*64 + d)*LQP;
  float s = 0.f;
  for (int c = seg; c < 98; c += 4){
    s8v v = *(const s8v*)(row + c*8);
    #pragma unroll
    for (int e=0;e<8;++e) s += b2f(v[e]);
  }
  s += __shfl_xor(s, 1, 64);
  s += __shfl_xor(s, 2, 64);
  if (seg == 0) Vm[nh*64 + d] = s * (1.0f/784.0f);
}

// ---------------- fused prep: patch pad+cast, 5 weight transposes, one launch ----------------
__device__ __forceinline__ void transp_body(long idx, const float* __restrict__ src,
                                            short* __restrict__ dst, int R, int C, int Rpad,
                                            long sStride, long dStride){
  long per = (long)C * Rpad;
  int z = (int)(idx / per);
  long rem = idx - (long)z * per;
  int cc = (int)(rem / Rpad);
  int r  = (int)(rem - (long)cc * Rpad);
  short v = 0;
  if (r < R) v = f2b(src[(long)z * sStride + (long)r * C + cc]);
  dst[(long)z * dStride + rem] = v;
}

#define PB0 43904   // padpatch
#define PB1 896     // Wemb
#define PB2 12288   // Wqkv
#define PB3 4096    // Wo
#define PB4 16384   // W1
#define PB5 16384   // W2

__global__ __launch_bounds__(256) void prep_k(
    const float* __restrict__ patch, short* __restrict__ patchb,
    const float* __restrict__ Wemb, short* __restrict__ Wembt,
    const float* __restrict__ Wqkv, short* __restrict__ Wqkvt,
    const float* __restrict__ Wo, short* __restrict__ Wot,
    const float* __restrict__ W1, short* __restrict__ W1t,
    const float* __restrict__ W2, short* __restrict__ W2t){
  int b = blockIdx.x;
  int tid = threadIdx.x;
  if (b < PB0){
    long idx = (long)b*256 + tid;
    if (idx >= (long)MROWS*KPAD) return;
    int r = (int)(idx / KPAD);
    int c = (int)(idx - (long)r*KPAD);
    patchb[idx] = (c < 432) ? f2b(patch[(long)r*432 + c]) : (short)0;
  } else if (b < PB0+PB1){
    long idx = (long)(b-PB0)*256 + tid;
    if (idx < 229376) transp_body(idx, Wemb, Wembt, 432, 512, 448, 0, 0);
  } else if (b < PB0+PB1+PB2){
    long idx = (long)(b-PB0-PB1)*256 + tid;
    if (idx < 3145728) transp_body(idx, Wqkv, Wqkvt, 512, 1536, 512, 512L*1536, 1536L*512);
  } else if (b < PB0+PB1+PB2+PB3){
    long idx = (long)(b-PB0-PB1-PB2)*256 + tid;
    if (idx < 1048576) transp_body(idx, Wo, Wot, 512, 512, 512, 512L*512, 512L*512);
  } else if (b < PB0+PB1+PB2+PB3+PB4){
    long idx = (long)(b-PB0-PB1-PB2-PB3)*256 + tid;
    if (idx < 4194304) transp_body(idx, W1, W1t, 512, 2048, 512, 512L*2048, 2048L*512);
  } else {
    long idx = (long)(b-PB0-PB1-PB2-PB3-PB4)*256 + tid;
    if (idx < 4194304) transp_body(idx, W2, W2t, 2048, 512, 2048, 2048L*512, 512L*2048);
  }
}

// ---------------- layernorm: 1 wave per 512-wide row, 4 rows/block ----------------
__global__ __launch_bounds__(256) void ln_k(const float* __restrict__ x, const float* __restrict__ g,
                                            const float* __restrict__ b, short* __restrict__ outb,
                                            float* __restrict__ outf){
  int lane = threadIdx.x & 63;
  long row = (long)blockIdx.x * 4 + (threadIdx.x >> 6);
  const float* xr = x + row * DIM + lane * 8;
  float va[8];
  { float4 t0 = *(const float4*)xr; float4 t1 = *(const float4*)(xr + 4);
    va[0]=t0.x; va[1]=t0.y; va[2]=t0.z; va[3]=t0.w;
    va[4]=t1.x; va[5]=t1.y; va[6]=t1.z; va[7]=t1.w; }
  float s = 0.f, q = 0.f;
  #pragma unroll
  for (int j=0;j<8;++j){ s += va[j]; q += va[j]*va[j]; }
  #pragma unroll
  for (int m=1;m<64;m<<=1){ s += __shfl_xor(s,m,64); q += __shfl_xor(q,m,64); }
  float mean = s * (1.0f/DIM);
  float var = q * (1.0f/DIM) - mean*mean;
  float inv = rsqrtf(var + 1e-5f);
  int cb = lane*8;
  if (outb){
    s8v o;
    #pragma unroll
    for (int j=0;j<8;++j) o[j] = f2b((va[j]-mean)*inv*g[cb+j] + b[cb+j]);
    *(s8v*)(outb + row*DIM + cb) = o;
  } else {
    float4 t0, t1;
    t0.x=(va[0]-mean)*inv*g[cb+0]+b[cb+0]; t0.y=(va[1]-mean)*inv*g[cb+1]+b[cb+1];
    t0.z=(va[2]-mean)*inv*g[cb+2]+b[cb+2]; t0.w=(va[3]-mean)*inv*g[cb+3]+b[cb+3];
    t1.x=(va[4]-mean)*inv*g[cb+4]+b[cb+4]; t1.y=(va[5]-mean)*inv*g[cb+5]+b[cb+5];
    t1.z=(va[6]-mean)*inv*g[cb+6]+b[cb+6]; t1.w=(va[7]-mean)*inv*g[cb+7]+b[cb+7];
    *(float4*)(outf + row*DIM + cb) = t0;
    *(float4*)(outf + row*DIM + cb + 4) = t1;
  }
}

// ---------------- 128x128 GEMM, 2-phase counted-vmcnt (embed / Wo) ----------------
template<int EPI>
__global__ __launch_bounds__(256) void gemm_k(
    const short* __restrict__ A, const short* __restrict__ Bt,
    const float* __restrict__ bias, int K, int N,
    float* __restrict__ xres, short* __restrict__ outb,
    const float* __restrict__ sp, const float* __restrict__ tp)
{
  __shared__ __align__(16) short lA[2][128*64];
  __shared__ __align__(16) short lB[2][128*64];
  long bm = blockIdx.y, bn = blockIdx.x;
  int tid = threadIdx.x;
  int lane = tid & 63, wid = tid >> 6;
  int col = lane & 15, quad = lane >> 4;
  int wm = (wid >> 1) * 64, wn = (wid & 1) * 64;
  f4v acc[4][4];
  #pragma unroll
  for (int i=0;i<4;++i)
    #pragma unroll
    for (int j=0;j<4;++j)
      #pragma unroll
      for (int e=0;e<4;++e) acc[i][j][e] = 0.0f;
  const short* Abase = A + bm*128*(long)K;
  const short* Bbase = Bt + bn*128*(long)K;
  int nt = K >> 6;
  #pragma unroll
  for (int c = 0; c < 4; ++c){
    int v = c*256 + tid;
    int r = v >> 3, j = v & 7;
    int kc = (j ^ (r & 7)) * 8;
    gll16(Abase + (long)r*K + kc, lA[0] + v*8);
    gll16(Bbase + (long)r*K + kc, lB[0] + v*8);
  }
  for (int t = 0; t < nt; ++t){
    int cur = t & 1;
    __builtin_amdgcn_s_barrier();
    __builtin_amdgcn_sched_barrier(0);
    if (t + 1 < nt){
      int kt = (t + 1) << 6;
      #pragma unroll
      for (int c = 0; c < 4; ++c){
        int v = c*256 + tid;
        int r = v >> 3, j = v & 7;
        int kc = (j ^ (r & 7)) * 8;
        gll16(Abase + (long)r*K + kt + kc, lA[cur^1] + v*8);
        gll16(Bbase + (long)r*K + kt + kc, lB[cur^1] + v*8);
      }
      asm volatile("s_waitcnt vmcnt(8)" ::: "memory");
    } else {
      asm volatile("s_waitcnt vmcnt(0)" ::: "memory");
    }
    __builtin_amdgcn_s_barrier();
    __builtin_amdgcn_sched_barrier(0);
    __builtin_amdgcn_s_setprio(1);
    #pragma unroll
    for (int ks = 0; ks < 2; ++ks){
      s8v af[4], bf[4];
      #pragma unroll
      for (int j=0;j<4;++j)
        af[j] = *(const s8v*)&lA[cur][(wm + j*16 + col)*64 + (((ks*4+quad) ^ (col&7)))*8];
      #pragma unroll
      for (int i=0;i<4;++i)
        bf[i] = *(const s8v*)&lB[cur][(wn + i*16 + col)*64 + (((ks*4+quad) ^ (col&7)))*8];
      #pragma unroll
      for (int i=0;i<4;++i)
        #pragma unroll
        for (int j=0;j<4;++j)
          acc[i][j] = __builtin_amdgcn_mfma_f32_16x16x32_bf16(bf[i], af[j], acc[i][j], 0, 0, 0);
    }
    __builtin_amdgcn_s_setprio(0);
    __builtin_amdgcn_sched_barrier(0);
  }
  #pragma unroll
  for (int j=0;j<4;++j){
    int grow = (int)bm*128 + wm + j*16 + col;
    int l = 0, t = 0, p = 0;
    if (EPI == 0){ l = grow % LQ; t = l / 49; p = l - t*49; }
    #pragma unroll
    for (int i=0;i<4;++i){
      int gc0 = (int)bn*128 + wn + i*16 + quad*4;
      float4 b4 = *(const float4*)(bias + gc0);
      float v0 = acc[i][j][0] + b4.x;
      float v1 = acc[i][j][1] + b4.y;
      float v2 = acc[i][j][2] + b4.z;
      float v3 = acc[i][j][3] + b4.w;
      if (EPI == 0){
        float4 s4 = *(const float4*)(sp + p*DIM + gc0);
        float4 t4 = *(const float4*)(tp + t*DIM + gc0);
        float4 o; o.x = v0 + s4.x + t4.x; o.y = v1 + s4.y + t4.y;
        o.z = v2 + s4.z + t4.z; o.w = v3 + s4.w + t4.w;
        *(float4*)(xres + (long)grow*DIM + gc0) = o;
      } else {   // EPI == 2: residual accumulate
        float4 xo = *(const float4*)(xres + (long)grow*DIM + gc0);
        xo.x += v0; xo.y += v1; xo.z += v2; xo.w += v3;
        *(float4*)(xres + (long)grow*DIM + gc0) = xo;
      }
    }
  }
}

// ---------------- 256x256 GEMM, 512 threads, 4-phase-per-K-tile pipeline ----------------
// Per phase: stage 1 half-tile (2 gll16/thread, uniform) -> (phase 0: vmcnt(2)+barrier
// = ENTIRE previous tile landed) -> ds_read one C-quadrant's frags -> lgkmcnt(0)+
// sched_barrier -> setprio(1) 16 MFMA setprio(0) -> barrier. vmcnt never drains in
// the loop; staging flows at 2 loads/phase; per-phase barriers let waves skew so
// ds_reads of one wave overlap MFMAs of another (T3+T4 structure).
template<int EPI>
__global__ __launch_bounds__(512) void gemm256_k(
    const short* __restrict__ A, const short* __restrict__ Bt,
    const float* __restrict__ bias, int K, int N,
    float* __restrict__ xres, short* __restrict__ outb,
    short* __restrict__ Qb, short* __restrict__ Kb, short* __restrict__ Vtb,
    const int* __restrict__ liveg)
{
  __shared__ __align__(16) short lA[2][2][128*64];   // [dbuf][half]
  __shared__ __align__(16) short lB[2][2][128*64];
  long bm = blockIdx.y, bn = blockIdx.x;
  if (EPI == 1){
    if (bn < 4 && liveg[4*bm] == 0 && liveg[4*bm+1] == 0 &&
        liveg[4*bm+2] == 0 && liveg[4*bm+3] == 0) return;
  }
  int tid = threadIdx.x;
  int lane = tid & 63, wid = tid >> 6;        // 8 waves: 2(M) x 4(N)
  int col = lane & 15, quad = lane >> 4;
  int wm = (wid >> 2) * 128;                  // A-half index mg = wid>>2
  int wn = (wid & 3) * 64;                    // B-half index bh = (wid&3)>>1
  int mg = wid >> 2;
  int bh = (wid & 3) >> 1;
  int bl = wn & 64;                           // local row base within B-half
  f4v acc[4][8];   // acc[i][j]: cols bn*256+wn+i*16+quad*4+(0..3), row bm*256+wm+j*16+col
  #pragma unroll
  for (int i=0;i<4;++i)
    #pragma unroll
    for (int j=0;j<8;++j)
      #pragma unroll
      for (int e=0;e<4;++e) acc[i][j][e] = 0.0f;
  const short* Abase = A + bm*256*(long)K;
  const short* Bbase = Bt + bn*256*(long)K;
  int nt = K >> 6;
  // stage one half-tile (128 rows x 64 k) = 2 gll16/thread, linear LDS + XOR'd source
  auto stageA = [&](int db, int h, int kt){
    #pragma unroll
    for (int c = 0; c < 2; ++c){
      int v = c*512 + tid;
      int r = v >> 3, j = v & 7;
      int kc = (j ^ (r & 7)) * 8;
      gll16(Abase + (long)(h*128 + r)*K + kt + kc, &lA[db][h][v*8]);
    }
  };
  auto stageB = [&](int db, int h, int kt){
    #pragma unroll
    for (int c = 0; c < 2; ++c){
      int v = c*512 + tid;
      int r = v >> 3, j = v & 7;
      int kc = (j ^ (r & 7)) * 8;
      gll16(Bbase + (long)(h*128 + r)*K + kt + kc, &lB[db][h][v*8]);
    }
  };
  // prologue: tile 0 -> dbuf 0 (8 loads/thread, stay in flight)
  stageA(0, 0, 0); stageA(0, 1, 0); stageB(0, 0, 0); stageB(0, 1, 0);
  s8v bf[4][2];
  for (int T = 0; T < nt; ++T){
    int db = T & 1;
    int ktn = (T + 1 < nt ? T + 1 : 0) << 6;   // clamped: uniform load counts
    #pragma unroll
    for (int q = 0; q < 4; ++q){
      // stage one half-tile of tile T+1 into dbuf[db^1]
      if (q == 0)      stageA(db^1, 0, ktn);
      else if (q == 1) stageA(db^1, 1, ktn);
      else if (q == 2) stageB(db^1, 0, ktn);
      else             stageB(db^1, 1, ktn);
      if (q == 0){
        // all stages of tile T were issued >= 4 phases ago; keep only this
        // phase's 2 loads in flight -> tile T fully in LDS for every wave
        asm volatile("s_waitcnt vmcnt(2)" ::: "memory");
        __builtin_amdgcn_s_barrier();
        __builtin_amdgcn_sched_barrier(0);
        #pragma unroll
        for (int i=0;i<4;++i)
          #pragma unroll
          for (int ks=0;ks<2;++ks)
            bf[i][ks] = *(const s8v*)&lB[db][bh][(bl + i*16 + col)*64 + (((ks*4+quad) ^ (col&7)))*8];
      }
      s8v af[2][2];
      #pragma unroll
      for (int jj=0;jj<2;++jj)
        #pragma unroll
        for (int ks=0;ks<2;++ks)
          af[jj][ks] = *(const s8v*)&lA[db][mg][((q*2+jj)*16 + col)*64 + (((ks*4+quad) ^ (col&7)))*8];
      asm volatile("s_waitcnt lgkmcnt(0)" ::: "memory");
      __builtin_amdgcn_sched_barrier(0);
      __builtin_amdgcn_s_setprio(1);
      #pragma unroll
      for (int ks=0;ks<2;++ks)
        #pragma unroll
        for (int i=0;i<4;++i)
          #pragma unroll
          for (int jj=0;jj<2;++jj)
            acc[i][q*2+jj] = __builtin_amdgcn_mfma_f32_16x16x32_bf16(bf[i][ks], af[jj][ks], acc[i][q*2+jj], 0, 0, 0);
      __builtin_amdgcn_s_setprio(0);
      __builtin_amdgcn_sched_barrier(0);
      __builtin_amdgcn_s_barrier();   // phase fence: bounds wave skew, closes WAR chain
    }
  }
  asm volatile("s_waitcnt vmcnt(0)" ::: "memory");   // drain stray clamped stages
  #pragma unroll
  for (int j=0;j<8;++j){
    int grow = (int)bm*256 + wm + j*16 + col;
    int n = 0, l = 0;
    if (EPI == 1){ n = grow / LQ; l = grow - n*LQ; }
    #pragma unroll
    for (int i=0;i<4;++i){
      int gc0 = (int)bn*256 + wn + i*16 + quad*4;
      float4 b4 = *(const float4*)(bias + gc0);
      float v0 = acc[i][j][0] + b4.x;
      float v1 = acc[i][j][1] + b4.y;
      float v2 = acc[i][j][2] + b4.z;
      float v3 = acc[i][j][3] + b4.w;
      if (EPI == 1){
        if (gc0 < 512){
          int hh = gc0 >> 6, d0 = gc0 & 63;
          s4v o; o[0]=f2b(v0); o[1]=f2b(v1); o[2]=f2b(v2); o[3]=f2b(v3);
          *(s4v*)(Qb + (((long)(n*HEADS + hh))*LQP + l)*64 + d0) = o;
        } else if (gc0 < 1024){
          int c2 = gc0 - 512; int hh = c2 >> 6, d0 = c2 & 63;
          s4v o; o[0]=f2b(v0); o[1]=f2b(v1); o[2]=f2b(v2); o[3]=f2b(v3);
          *(s4v*)(Kb + (((long)(n*HEADS + hh))*LQP + l)*64 + d0) = o;
        } else {
          int c2 = gc0 - 1024; int hh = c2 >> 6, d0 = c2 & 63;
          long base = ((long)(n*HEADS + hh))*64;
          Vtb[(base + d0+0)*LQP + l] = f2b(v0);
          Vtb[(base + d0+1)*LQP + l] = f2b(v1);
          Vtb[(base + d0+2)*LQP + l] = f2b(v2);
          Vtb[(base + d0+3)*LQP + l] = f2b(v3);
        }
      } else if (EPI == 2){   // residual accumulate into fp32 x
        float4 xo = *(const float4*)(xres + (long)grow*DIM + gc0);
        xo.x += v0; xo.y += v1; xo.z += v2; xo.w += v3;
        *(float4*)(xres + (long)grow*DIM + gc0) = xo;
      } else {   // EPI == 3: gelu -> bf16
        float g0 = v0 / (1.0f + __expf(-1.595769122f * v0 * (1.0f + 0.044715f*v0*v0)));
        float g1 = v1 / (1.0f + __expf(-1.595769122f * v1 * (1.0f + 0.044715f*v1*v1)));
        float g2 = v2 / (1.0f + __expf(-1.595769122f * v2 * (1.0f + 0.044715f*v2*v2)));
        float g3 = v3 / (1.0f + __expf(-1.595769122f * v3 * (1.0f + 0.044715f*v3*v3)));
        s4v o; o[0]=f2b(g0); o[1]=f2b(g1); o[2]=f2b(g2); o[3]=f2b(g3);
        *(s4v*)(outb + (long)grow*MLP + gc0) = o;
      }
    }
  }
}

// ---------------- sparse flash attention (unchanged) ----------------
__global__ __launch_bounds__(256) void attn_k(
    const short* __restrict__ Qb, const short* __restrict__ Kb,
    const short* __restrict__ Vtb, const float* __restrict__ keepL,
    const int* __restrict__ kmask, const float* __restrict__ Vm,
    short* __restrict__ Ob)
{
  __shared__ __align__(16) short lK[64*64];
  __shared__ __align__(16) short lV[64*64];
  __shared__ __align__(16) short lP[4][16*72];
  int tid = threadIdx.x;
  int lane = tid & 63, wid = tid >> 6;
  int col = lane & 15, quad = lane >> 4;
  int qb = blockIdx.x, h = blockIdx.y, n = blockIdx.z;
  long nh = (long)n*HEADS + h;
  int smask = kmask[n];
  int qr0 = qb*64 + wid*16;
  float vmv[4];
  #pragma unroll
  for (int j=0;j<4;++j) vmv[j] = Vm[nh*64 + j*16 + col];

  if (!((smask >> qb) & 1)){
    #pragma unroll
    for (int j=0;j<4;++j){
      short ov = f2b(vmv[j]);
      #pragma unroll
      for (int r=0;r<4;++r){
        int l = qr0 + quad*4 + r;
        if (l < LQ) Ob[((long)n*LQ + l)*DIM + h*64 + j*16 + col] = ov;
      }
    }
    return;
  }

  const float* kl = keepL + n*LQP;
  const short* qp = Qb + (nh*LQP + qr0 + col)*64 + quad*8;
  s8v aq0 = *(const s8v*)qp;
  s8v aq1 = *(const s8v*)(qp + 32);
  float keepA = kl[qr0 + col];
  if (keepA < 0.5f){
    #pragma unroll
    for (int e=0;e<8;++e){ aq0[e] = 0; aq1[e] = 0; }
  }
  float keepQ[4];
  #pragma unroll
  for (int r=0;r<4;++r) keepQ[r] = kl[qr0 + quad*4 + r];
  float kqs = keepQ[0] + keepQ[1] + keepQ[2] + keepQ[3];
  bool wlive = __ballot(kqs > 0.5f) != 0ull;
  float lsum[4] = {0.f,0.f,0.f,0.f};
  f4v Oacc[4];
  #pragma unroll
  for (int j=0;j<4;++j)
    #pragma unroll
    for (int e=0;e<4;++e) Oacc[j][e] = 0.0f;

  for (int kb = 0; kb < 13; ++kb){
    if (!((smask >> kb) & 1)) continue;
    int kbase = kb*64;
    __syncthreads();
    #pragma unroll
    for (int c = 0; c < 2; ++c){
      int v = c*256 + tid;
      int r = v >> 3, j = v & 7;
      int kc = (j ^ (r & 7)) * 8;
      gll16(Kb + (nh*LQP + kbase + r)*64 + kc, lK + v*8);
    }
    #pragma unroll
    for (int c = 0; c < 2; ++c){
      int v = c*256 + tid;
      int d = v >> 3, j = v & 7;
      int c8 = (j ^ (d & 7)) * 8;
      gll16(Vtb + (nh*64 + d)*LQP + kbase + c8, lV + v*8);
    }
    __syncthreads();
    if (!wlive) continue;
    float pm[4][4];
    #pragma unroll
    for (int ct = 0; ct < 4; ++ct){
      float keepK = kl[kbase + ct*16 + col];
      f4v s;
      #pragma unroll
      for (int e=0;e<4;++e) s[e] = 0.0f;
      #pragma unroll
      for (int ks = 0; ks < 2; ++ks){
        s8v bk = *(const s8v*)&lK[(ct*16 + col)*64 + (((ks*4+quad) ^ (col&7)))*8];
        if (keepK < 0.5f){
          #pragma unroll
          for (int e=0;e<8;++e) bk[e] = 0;
        }
        s = __builtin_amdgcn_mfma_f32_16x16x32_bf16(ks ? aq1 : aq0, bk, s, 0, 0, 0);
      }
      #pragma unroll
      for (int r=0;r<4;++r){
        float a = keepQ[r] * keepK;
        float t = fmaf(s[r], 0.125f, 10000.0f);
        float p = __expf(fmaf(a, t, -10000.0f));
        pm[ct][r] = p;
        lsum[r] += p;
      }
    }
    #pragma unroll
    for (int ct=0; ct<4; ++ct)
      #pragma unroll
      for (int r=0;r<4;++r)
        lP[wid][(quad*4 + r)*72 + ct*16 + col] = f2b(pm[ct][r]);
    #pragma unroll
    for (int j=0;j<4;++j){
      #pragma unroll
      for (int ks=0; ks<2; ++ks){
        s8v ap = *(const s8v*)&lP[wid][col*72 + ks*32 + quad*8];
        s8v bv = *(const s8v*)&lV[(j*16 + col)*64 + (((ks*4+quad) ^ (col&7)))*8];
        Oacc[j] = __builtin_amdgcn_mfma_f32_16x16x32_bf16(ap, bv, Oacc[j], 0, 0, 0);
      }
    }
  }
  #pragma unroll
  for (int m=1; m<16; m<<=1){
    #pragma unroll
    for (int r=0;r<4;++r) lsum[r] += __shfl_xor(lsum[r], m, 64);
  }
  float invl[4];
  #pragma unroll
  for (int r=0;r<4;++r) invl[r] = 1.0f / lsum[r];
  #pragma unroll
  for (int j=0;j<4;++j)
    #pragma unroll
    for (int r=0;r<4;++r){
      int l = qr0 + quad*4 + r;
      if (l < LQ){
        float val = keepQ[r] > 0.5f ? Oacc[j][r] * invl[r] : vmv[j];
        Ob[((long)n*LQ + l)*DIM + h*64 + j*16 + col] = f2b(val);
      }
    }
}

// ---------------- host ----------------
extern "C" void kernel_launch(void* const* d_in, const int* in_sizes, int n_in,
                              void* d_out, int out_size, void* d_ws, size_t ws_size,
                              hipStream_t stream) {
  const float* patch    = (const float*)d_in[0];
  const int*   done     = (const int*)d_in[1];
  const float* W_embed  = (const float*)d_in[2];
  const float* b_embed  = (const float*)d_in[3];
  const float* spatial  = (const float*)d_in[4];
  const float* temporal = (const float*)d_in[5];
  const float* ln1_g    = (const float*)d_in[6];
  const float* ln1_b    = (const float*)d_in[7];
  const float* Wqkv     = (const float*)d_in[8];
  const float* bqkv     = (const float*)d_in[9];
  const float* Wo       = (const float*)d_in[10];
  const float* bo       = (const float*)d_in[11];
  const float* ln2_g    = (const float*)d_in[12];
  const float* ln2_b    = (const float*)d_in[13];
  const float* W1       = (const float*)d_in[14];
  const float* b1       = (const float*)d_in[15];
  const float* W2       = (const float*)d_in[16];
  const float* b2       = (const float*)d_in[17];
  const float* out_g    = (const float*)d_in[18];
  const float* out_b    = (const float*)d_in[19];
  float* out = (float*)d_out;

  char* ws = (char*)d_ws;
  size_t off = 0;
  auto alloc = [&](size_t bytes)->char*{ char* p = ws + off; off += (bytes + 255) & ~(size_t)255; return p; };
  const size_t QKV_B = (size_t)NB*HEADS*LQP*64*2;
  float* x    = (float*)alloc((size_t)MROWS*DIM*4);
  short* hbuf = (short*)alloc((size_t)MROWS*DIM*2);
  char*  U    = alloc((size_t)MROWS*MLP*2);
  short* patchb = (short*)U;
  short* Qb   = (short*)U;
  short* Kbf  = (short*)(U + QKV_B);
  short* Vtb  = (short*)(U + 2*QKV_B);
  short* obuf = hbuf;
  short* mid  = (short*)U;
  short* Wembt = (short*)alloc((size_t)512*448*2);
  short* Wqkvt = (short*)alloc((size_t)4*1536*512*2);
  short* Wot   = (short*)alloc((size_t)4*512*512*2);
  short* W1t   = (short*)alloc((size_t)4*2048*512*2);
  short* W2t   = (short*)alloc((size_t)4*512*2048*2);
  float* keepL = (float*)alloc((size_t)NB*LQP*4);
  int*   kmask = (int*)alloc(NB*4);
  int*   liveg = (int*)alloc(392*4);
  float* Vm    = (float*)alloc((size_t)NB*HEADS*64*4);

  mask_k<<<1, 512, 0, stream>>>(done, keepL, kmask, liveg);
  prep_k<<<PB0+PB1+PB2+PB3+PB4+PB5, 256, 0, stream>>>(
      patch, patchb, W_embed, Wembt, Wqkv, Wqkvt, Wo, Wot, W1, W1t, W2, W2t);

  gemm_k<0><<<dim3(DIM/128, MROWS/128), 256, 0, stream>>>(
      patchb, Wembt, b_embed, KPAD, DIM, x, nullptr, spatial, temporal);

  zpad_k<<<1152, 256, 0, stream>>>(Qb, Kbf, Vtb);

  for (int i = 0; i < 4; ++i){
    ln_k<<<MROWS/4, 256, 0, stream>>>(x, ln1_g + i*DIM, ln1_b + i*DIM, hbuf, nullptr);
    gemm256_k<1><<<dim3(1536/256, MROWS/256), 512, 0, stream>>>(
        hbuf, Wqkvt + (size_t)i*1536*512, bqkv + (size_t)i*1536, DIM, 1536,
        nullptr, nullptr, Qb, Kbf, Vtb, liveg);
    vmean_k<<<NB*HEADS, 256, 0, stream>>>(Vtb, Vm);
    attn_k<<<dim3(13, HEADS, NB), 256, 0, stream>>>(Qb, Kbf, Vtb, keepL, kmask, Vm, obuf);
    gemm_k<2><<<dim3(DIM/128, MROWS/128), 256, 0, stream>>>(
        obuf, Wot + (size_t)i*512*512, bo + (size_t)i*DIM, DIM, DIM,
        x, nullptr, nullptr, nullptr);
    ln_k<<<MROWS/4, 256, 0, stream>>>(x, ln2_g + i*DIM, ln2_b + i*DIM, hbuf, nullptr);
    gemm256_k<3><<<dim3(MLP/256, MROWS/256), 512, 0, stream>>>(
        hbuf, W1t + (size_t)i*2048*512, b1 + (size_t)i*MLP, DIM, MLP,
        nullptr, mid, nullptr, nullptr, nullptr, nullptr);
    gemm256_k<2><<<dim3(DIM/256, MROWS/256), 512, 0, stream>>>(
        mid, W2t + (size_t)i*512*2048, b2 + (size_t)i*DIM, MLP, DIM,
        x, nullptr, nullptr, nullptr, nullptr, nullptr);
  }
  ln_k<<<MROWS/4, 256, 0, stream>>>(x, out_g, out_b, nullptr, out);
}

// Round 5
// 1742.596 us; speedup vs baseline: 1.0937x; 1.0937x over previous
//
#include <hip/hip_runtime.h>
#include <math.h>

#define NB 32
#define LQ 784
#define LQP 832   // 13*64, padded sequence length for attention buffers
#define DIM 512
#define HEADS 8
#define MLP 2048
#define KPAD 448
#define MROWS 25088  // NB*LQ

typedef __attribute__((ext_vector_type(8))) short s8v;
typedef __attribute__((ext_vector_type(4))) short s4v;
typedef __attribute__((ext_vector_type(4))) float f4v;

__device__ __forceinline__ short f2b(float f){
  unsigned u = __builtin_bit_cast(unsigned, f);
  u = (u + 0x7fffu + ((u >> 16) & 1u)) >> 16;
  return (short)u;
}
__device__ __forceinline__ float b2f(short s){
  unsigned u = ((unsigned)(unsigned short)s) << 16;
  return __builtin_bit_cast(float, u);
}

// async global->LDS, 16B per lane. LDS dest pattern must be wave-uniform base + lane*16.
__device__ __forceinline__ void gll16(const short* g, short* l){
  __builtin_amdgcn_global_load_lds(
      (const __attribute__((address_space(1))) void*)g,
      (__attribute__((address_space(3))) void*)l, 16, 0, 0);
}

// ---------------- fused mask prep (single block) ----------------
__global__ __launch_bounds__(512) void mask_k(const int* __restrict__ done, float* __restrict__ keepL,
                                              int* __restrict__ kmask, int* __restrict__ liveg){
  __shared__ float keep[32][16];
  int tid = threadIdx.x;
  { int n = tid >> 4, t = tid & 15;
    int any = 0;
    for (int c = t; c < 15; ++c) any |= done[n*15 + c];
    keep[n][t] = any ? 0.f : 1.f; }
  __syncthreads();
  for (int i = tid; i < NB*LQP; i += 512){
    int n = i / LQP, l = i - n*LQP;
    keepL[i] = (l < LQ) ? keep[n][l/49] : 0.f;
  }
  if (tid < 32){
    int n = tid, m = 0;
    for (int kb = 0; kb < 13; ++kb){
      int t0 = (kb*64)/49, t1 = (kb*64 + 63)/49; if (t1 > 15) t1 = 15;
      float a = 0.f;
      for (int t = t0; t <= t1; ++t) a += keep[n][t];
      if (a > 0.5f) m |= 1 << kb;
    }
    kmask[n] = m;
  }
  for (int g = tid; g < 392; g += 512){
    float a = 0.f;
    for (int i2 = 0; i2 < 64; ++i2){
      int row = g*64 + i2;
      int n = row / 784, l = row - n*784;
      a += keep[n][l/49];
    }
    liveg[g] = a > 0.5f ? 1 : 0;
  }
}

// zero pad rows/cols once, vectorized s8v stores
__global__ __launch_bounds__(256) void zpad_k(short* __restrict__ Qb, short* __restrict__ Kb,
                                              short* __restrict__ Vtb){
  int idx = blockIdx.x*256 + threadIdx.x;   // < 294912
  s8v z;
  #pragma unroll
  for (int e=0;e<8;++e) z[e] = 0;
  if (idx < 98304){
    int nh = idx / 384, r = idx - nh*384;
    *(s8v*)(Qb + (long)nh*LQP*64 + 784*64 + r*8) = z;
  } else if (idx < 196608){
    int i2 = idx - 98304; int nh = i2 / 384, r = i2 - nh*384;
    *(s8v*)(Kb + (long)nh*LQP*64 + 784*64 + r*8) = z;
  } else {
    int i2 = idx - 196608; int nh = i2 / 384, rem = i2 - nh*384, d = rem/6, s = rem - d*6;
    *(s8v*)(Vtb + ((long)nh*64 + d)*LQP + 784 + s*8) = z;
  }
}

// Vm[nh*64+d] = mean over l<784 of V  (V^T layout)
__global__ __launch_bounds__(256) void vmean_k(const short* __restrict__ Vtb, float* __restrict__ Vm){
  int nh = blockIdx.x;
  int tid = threadIdx.x;
  int d = tid >> 2, seg = tid & 3;
  const short* row = Vtb + ((long)nh*64 + d)*LQP;
  float s = 0.f;
  for (int c = seg; c < 98; c += 4){
    s8v v = *(const s8v*)(row + c*8);
    #pragma unroll
    for (int e=0;e<8;++e) s += b2f(v[e]);
  }
  s += __shfl_xor(s, 1, 64);
  s += __shfl_xor(s, 2, 64);
  if (seg == 0) Vm[nh*64 + d] = s * (1.0f/784.0f);
}

// ---------------- fused prep: patch pad+cast, 5 weight transposes, one launch ----------------
__device__ __forceinline__ void transp_body(long idx, const float* __restrict__ src,
                                            short* __restrict__ dst, int R, int C, int Rpad,
                                            long sStride, long dStride){
  long per = (long)C * Rpad;
  int z = (int)(idx / per);
  long rem = idx - (long)z * per;
  int cc = (int)(rem / Rpad);
  int r  = (int)(rem - (long)cc * Rpad);
  short v = 0;
  if (r < R) v = f2b(src[(long)z * sStride + (long)r * C + cc]);
  dst[(long)z * dStride + rem] = v;
}

#define PB0 43904   // padpatch
#define PB1 896     // Wemb
#define PB2 12288   // Wqkv
#define PB3 4096    // Wo
#define PB4 16384   // W1
#define PB5 16384   // W2

__global__ __launch_bounds__(256) void prep_k(
    const float* __restrict__ patch, short* __restrict__ patchb,
    const float* __restrict__ Wemb, short* __restrict__ Wembt,
    const float* __restrict__ Wqkv, short* __restrict__ Wqkvt,
    const float* __restrict__ Wo, short* __restrict__ Wot,
    const float* __restrict__ W1, short* __restrict__ W1t,
    const float* __restrict__ W2, short* __restrict__ W2t){
  int b = blockIdx.x;
  int tid = threadIdx.x;
  if (b < PB0){
    long idx = (long)b*256 + tid;
    if (idx >= (long)MROWS*KPAD) return;
    int r = (int)(idx / KPAD);
    int c = (int)(idx - (long)r*KPAD);
    patchb[idx] = (c < 432) ? f2b(patch[(long)r*432 + c]) : (short)0;
  } else if (b < PB0+PB1){
    long idx = (long)(b-PB0)*256 + tid;
    if (idx < 229376) transp_body(idx, Wemb, Wembt, 432, 512, 448, 0, 0);
  } else if (b < PB0+PB1+PB2){
    long idx = (long)(b-PB0-PB1)*256 + tid;
    if (idx < 3145728) transp_body(idx, Wqkv, Wqkvt, 512, 1536, 512, 512L*1536, 1536L*512);
  } else if (b < PB0+PB1+PB2+PB3){
    long idx = (long)(b-PB0-PB1-PB2)*256 + tid;
    if (idx < 1048576) transp_body(idx, Wo, Wot, 512, 512, 512, 512L*512, 512L*512);
  } else if (b < PB0+PB1+PB2+PB3+PB4){
    long idx = (long)(b-PB0-PB1-PB2-PB3)*256 + tid;
    if (idx < 4194304) transp_body(idx, W1, W1t, 512, 2048, 512, 512L*2048, 2048L*512);
  } else {
    long idx = (long)(b-PB0-PB1-PB2-PB3-PB4)*256 + tid;
    if (idx < 4194304) transp_body(idx, W2, W2t, 2048, 512, 2048, 2048L*512, 512L*2048);
  }
}

// ---------------- layernorm: 1 wave per 512-wide row, 4 rows/block ----------------
__global__ __launch_bounds__(256) void ln_k(const float* __restrict__ x, const float* __restrict__ g,
                                            const float* __restrict__ b, short* __restrict__ outb,
                                            float* __restrict__ outf){
  int lane = threadIdx.x & 63;
  long row = (long)blockIdx.x * 4 + (threadIdx.x >> 6);
  const float* xr = x + row * DIM + lane * 8;
  float va[8];
  { float4 t0 = *(const float4*)xr; float4 t1 = *(const float4*)(xr + 4);
    va[0]=t0.x; va[1]=t0.y; va[2]=t0.z; va[3]=t0.w;
    va[4]=t1.x; va[5]=t1.y; va[6]=t1.z; va[7]=t1.w; }
  float s = 0.f, q = 0.f;
  #pragma unroll
  for (int j=0;j<8;++j){ s += va[j]; q += va[j]*va[j]; }
  #pragma unroll
  for (int m=1;m<64;m<<=1){ s += __shfl_xor(s,m,64); q += __shfl_xor(q,m,64); }
  float mean = s * (1.0f/DIM);
  float var = q * (1.0f/DIM) - mean*mean;
  float inv = rsqrtf(var + 1e-5f);
  int cb = lane*8;
  if (outb){
    s8v o;
    #pragma unroll
    for (int j=0;j<8;++j) o[j] = f2b((va[j]-mean)*inv*g[cb+j] + b[cb+j]);
    *(s8v*)(outb + row*DIM + cb) = o;
  } else {
    float4 t0, t1;
    t0.x=(va[0]-mean)*inv*g[cb+0]+b[cb+0]; t0.y=(va[1]-mean)*inv*g[cb+1]+b[cb+1];
    t0.z=(va[2]-mean)*inv*g[cb+2]+b[cb+2]; t0.w=(va[3]-mean)*inv*g[cb+3]+b[cb+3];
    t1.x=(va[4]-mean)*inv*g[cb+4]+b[cb+4]; t1.y=(va[5]-mean)*inv*g[cb+5]+b[cb+5];
    t1.z=(va[6]-mean)*inv*g[cb+6]+b[cb+6]; t1.w=(va[7]-mean)*inv*g[cb+7]+b[cb+7];
    *(float4*)(outf + row*DIM + cb) = t0;
    *(float4*)(outf + row*DIM + cb + 4) = t1;
  }
}

// ---------------- GEMM with operand-swapped MFMA (acc = C^T) ----------------
// 2-phase double-buffered, counted vmcnt (round-2 schedule), BK=32:
// LDS = 2buf x (128x32) x 2ops x 2B = 32 KB -> 5 blocks/CU (20 waves) so
// independent blocks hide each other's barrier/latency stalls (r0's TLP)
// while the counted vmcnt keeps next-tile loads in flight across barriers
// (r2's pipelining). Same swizzle family (2-bit XOR), same epilogues.
template<int EPI>
__global__ __launch_bounds__(256) void gemm_k(
    const short* __restrict__ A, const short* __restrict__ Bt,
    const float* __restrict__ bias, int K, int N,
    float* __restrict__ xres, short* __restrict__ outb,
    const float* __restrict__ sp, const float* __restrict__ tp,
    short* __restrict__ Qb, short* __restrict__ Kb, short* __restrict__ Vtb,
    const int* __restrict__ liveg)
{
  __shared__ __align__(16) short lA[2][128*32];
  __shared__ __align__(16) short lB[2][128*32];
  long bm = blockIdx.y, bn = blockIdx.x;
  if (EPI == 1){
    if (bn < 8 && liveg[2*bm] == 0 && liveg[2*bm+1] == 0) return;
  }
  int tid = threadIdx.x;
  int lane = tid & 63, wid = tid >> 6;
  int col = lane & 15, quad = lane >> 4;
  int wm = (wid >> 1) * 64, wn = (wid & 1) * 64;
  f4v acc[4][4];   // acc[i][j]: cols wn+i*16+quad*4+(0..3), row wm+j*16+col
  #pragma unroll
  for (int i=0;i<4;++i)
    #pragma unroll
    for (int j=0;j<4;++j)
      #pragma unroll
      for (int e=0;e<4;++e) acc[i][j][e] = 0.0f;
  const short* Abase = A + bm*128*(long)K;
  const short* Bbase = Bt + bn*128*(long)K;
  int nt = K >> 5;
  // prologue: stage K-tile 0 into buffer 0 (4 loads/thread, stay in flight)
  #pragma unroll
  for (int c = 0; c < 2; ++c){
    int v = c*256 + tid;          // v < 512 : 128 rows x 4 chunks
    int r = v >> 2, j = v & 3;
    int kc = (j ^ (r & 3)) * 8;
    gll16(Abase + (long)r*K + kc, lA[0] + v*8);
    gll16(Bbase + (long)r*K + kc, lB[0] + v*8);
  }
  for (int t = 0; t < nt; ++t){
    int cur = t & 1;
    __builtin_amdgcn_s_barrier();              // buf[cur^1] free (read finished in t-1)
    __builtin_amdgcn_sched_barrier(0);
    if (t + 1 < nt){
      int kt = (t + 1) << 5;
      #pragma unroll
      for (int c = 0; c < 2; ++c){
        int v = c*256 + tid;
        int r = v >> 2, j = v & 3;
        int kc = (j ^ (r & 3)) * 8;
        gll16(Abase + (long)r*K + kt + kc, lA[cur^1] + v*8);
        gll16(Bbase + (long)r*K + kt + kc, lB[cur^1] + v*8);
      }
      asm volatile("s_waitcnt vmcnt(4)" ::: "memory");   // stage(t) done; t+1 in flight
    } else {
      asm volatile("s_waitcnt vmcnt(0)" ::: "memory");   // last tile: drain
    }
    __builtin_amdgcn_s_barrier();              // stage(t) visible to all waves
    __builtin_amdgcn_sched_barrier(0);
    __builtin_amdgcn_s_setprio(1);
    {
      s8v af[4], bf[4];
      #pragma unroll
      for (int j=0;j<4;++j)
        af[j] = *(const s8v*)&lA[cur][(wm + j*16 + col)*32 + ((quad ^ (col&3)))*8];
      #pragma unroll
      for (int i=0;i<4;++i)
        bf[i] = *(const s8v*)&lB[cur][(wn + i*16 + col)*32 + ((quad ^ (col&3)))*8];
      #pragma unroll
      for (int i=0;i<4;++i)
        #pragma unroll
        for (int j=0;j<4;++j)
          acc[i][j] = __builtin_amdgcn_mfma_f32_16x16x32_bf16(bf[i], af[j], acc[i][j], 0, 0, 0);
    }
    __builtin_amdgcn_s_setprio(0);
    __builtin_amdgcn_sched_barrier(0);
  }
  #pragma unroll
  for (int j=0;j<4;++j){
    int grow = (int)bm*128 + wm + j*16 + col;
    int l = 0, t = 0, p = 0, n = 0;
    if (EPI == 0){ l = grow % LQ; t = l / 49; p = l - t*49; }
    if (EPI == 1){ n = grow / LQ; l = grow - n*LQ; }
    #pragma unroll
    for (int i=0;i<4;++i){
      int gc0 = (int)bn*128 + wn + i*16 + quad*4;
      float4 b4 = *(const float4*)(bias + gc0);
      float v0 = acc[i][j][0] + b4.x;
      float v1 = acc[i][j][1] + b4.y;
      float v2 = acc[i][j][2] + b4.z;
      float v3 = acc[i][j][3] + b4.w;
      if (EPI == 0){
        float4 s4 = *(const float4*)(sp + p*DIM + gc0);
        float4 t4 = *(const float4*)(tp + t*DIM + gc0);
        float4 o; o.x = v0 + s4.x + t4.x; o.y = v1 + s4.y + t4.y;
        o.z = v2 + s4.z + t4.z; o.w = v3 + s4.w + t4.w;
        *(float4*)(xres + (long)grow*DIM + gc0) = o;
      } else if (EPI == 1){
        if (gc0 < 512){
          int hh = gc0 >> 6, d0 = gc0 & 63;
          s4v o; o[0]=f2b(v0); o[1]=f2b(v1); o[2]=f2b(v2); o[3]=f2b(v3);
          *(s4v*)(Qb + (((long)(n*HEADS + hh))*LQP + l)*64 + d0) = o;
        } else if (gc0 < 1024){
          int c2 = gc0 - 512; int hh = c2 >> 6, d0 = c2 & 63;
          s4v o; o[0]=f2b(v0); o[1]=f2b(v1); o[2]=f2b(v2); o[3]=f2b(v3);
          *(s4v*)(Kb + (((long)(n*HEADS + hh))*LQP + l)*64 + d0) = o;
        } else {
          int c2 = gc0 - 1024; int hh = c2 >> 6, d0 = c2 & 63;
          long base = ((long)(n*HEADS + hh))*64;
          Vtb[(base + d0+0)*LQP + l] = f2b(v0);
          Vtb[(base + d0+1)*LQP + l] = f2b(v1);
          Vtb[(base + d0+2)*LQP + l] = f2b(v2);
          Vtb[(base + d0+3)*LQP + l] = f2b(v3);
        }
      } else if (EPI == 2){
        float4 xo = *(const float4*)(xres + (long)grow*DIM + gc0);
        xo.x += v0; xo.y += v1; xo.z += v2; xo.w += v3;
        *(float4*)(xres + (long)grow*DIM + gc0) = xo;
      } else if (EPI == 3){
        float g0 = v0 / (1.0f + __expf(-1.595769122f * v0 * (1.0f + 0.044715f*v0*v0)));
        float g1 = v1 / (1.0f + __expf(-1.595769122f * v1 * (1.0f + 0.044715f*v1*v1)));
        float g2 = v2 / (1.0f + __expf(-1.595769122f * v2 * (1.0f + 0.044715f*v2*v2)));
        float g3 = v3 / (1.0f + __expf(-1.595769122f * v3 * (1.0f + 0.044715f*v3*v3)));
        s4v o; o[0]=f2b(g0); o[1]=f2b(g1); o[2]=f2b(g2); o[3]=f2b(g3);
        *(s4v*)(outb + (long)grow*MLP + gc0) = o;
      }
    }
  }
}

// ---------------- sparse flash attention (unchanged) ----------------
__global__ __launch_bounds__(256) void attn_k(
    const short* __restrict__ Qb, const short* __restrict__ Kb,
    const short* __restrict__ Vtb, const float* __restrict__ keepL,
    const int* __restrict__ kmask, const float* __restrict__ Vm,
    short* __restrict__ Ob)
{
  __shared__ __align__(16) short lK[64*64];
  __shared__ __align__(16) short lV[64*64];
  __shared__ __align__(16) short lP[4][16*72];
  int tid = threadIdx.x;
  int lane = tid & 63, wid = tid >> 6;
  int col = lane & 15, quad = lane >> 4;
  int qb = blockIdx.x, h = blockIdx.y, n = blockIdx.z;
  long nh = (long)n*HEADS + h;
  int smask = kmask[n];
  int qr0 = qb*64 + wid*16;
  float vmv[4];
  #pragma unroll
  for (int j=0;j<4;++j) vmv[j] = Vm[nh*64 + j*16 + col];

  if (!((smask >> qb) & 1)){
    #pragma unroll
    for (int j=0;j<4;++j){
      short ov = f2b(vmv[j]);
      #pragma unroll
      for (int r=0;r<4;++r){
        int l = qr0 + quad*4 + r;
        if (l < LQ) Ob[((long)n*LQ + l)*DIM + h*64 + j*16 + col] = ov;
      }
    }
    return;
  }

  const float* kl = keepL + n*LQP;
  const short* qp = Qb + (nh*LQP + qr0 + col)*64 + quad*8;
  s8v aq0 = *(const s8v*)qp;
  s8v aq1 = *(const s8v*)(qp + 32);
  float keepA = kl[qr0 + col];
  if (keepA < 0.5f){
    #pragma unroll
    for (int e=0;e<8;++e){ aq0[e] = 0; aq1[e] = 0; }
  }
  float keepQ[4];
  #pragma unroll
  for (int r=0;r<4;++r) keepQ[r] = kl[qr0 + quad*4 + r];
  float kqs = keepQ[0] + keepQ[1] + keepQ[2] + keepQ[3];
  bool wlive = __ballot(kqs > 0.5f) != 0ull;
  float lsum[4] = {0.f,0.f,0.f,0.f};
  f4v Oacc[4];
  #pragma unroll
  for (int j=0;j<4;++j)
    #pragma unroll
    for (int e=0;e<4;++e) Oacc[j][e] = 0.0f;

  for (int kb = 0; kb < 13; ++kb){
    if (!((smask >> kb) & 1)) continue;
    int kbase = kb*64;
    __syncthreads();
    #pragma unroll
    for (int c = 0; c < 2; ++c){
      int v = c*256 + tid;
      int r = v >> 3, j = v & 7;
      int kc = (j ^ (r & 7)) * 8;
      gll16(Kb + (nh*LQP + kbase + r)*64 + kc, lK + v*8);
    }
    #pragma unroll
    for (int c = 0; c < 2; ++c){
      int v = c*256 + tid;
      int d = v >> 3, j = v & 7;
      int c8 = (j ^ (d & 7)) * 8;
      gll16(Vtb + (nh*64 + d)*LQP + kbase + c8, lV + v*8);
    }
    __syncthreads();
    if (!wlive) continue;
    float pm[4][4];
    #pragma unroll
    for (int ct = 0; ct < 4; ++ct){
      float keepK = kl[kbase + ct*16 + col];
      f4v s;
      #pragma unroll
      for (int e=0;e<4;++e) s[e] = 0.0f;
      #pragma unroll
      for (int ks = 0; ks < 2; ++ks){
        s8v bk = *(const s8v*)&lK[(ct*16 + col)*64 + (((ks*4+quad) ^ (col&7)))*8];
        if (keepK < 0.5f){
          #pragma unroll
          for (int e=0;e<8;++e) bk[e] = 0;
        }
        s = __builtin_amdgcn_mfma_f32_16x16x32_bf16(ks ? aq1 : aq0, bk, s, 0, 0, 0);
      }
      #pragma unroll
      for (int r=0;r<4;++r){
        float a = keepQ[r] * keepK;
        float t = fmaf(s[r], 0.125f, 10000.0f);
        float p = __expf(fmaf(a, t, -10000.0f));
        pm[ct][r] = p;
        lsum[r] += p;
      }
    }
    #pragma unroll
    for (int ct=0; ct<4; ++ct)
      #pragma unroll
      for (int r=0;r<4;++r)
        lP[wid][(quad*4 + r)*72 + ct*16 + col] = f2b(pm[ct][r]);
    #pragma unroll
    for (int j=0;j<4;++j){
      #pragma unroll
      for (int ks=0; ks<2; ++ks){
        s8v ap = *(const s8v*)&lP[wid][col*72 + ks*32 + quad*8];
        s8v bv = *(const s8v*)&lV[(j*16 + col)*64 + (((ks*4+quad) ^ (col&7)))*8];
        Oacc[j] = __builtin_amdgcn_mfma_f32_16x16x32_bf16(ap, bv, Oacc[j], 0, 0, 0);
      }
    }
  }
  #pragma unroll
  for (int m=1; m<16; m<<=1){
    #pragma unroll
    for (int r=0;r<4;++r) lsum[r] += __shfl_xor(lsum[r], m, 64);
  }
  float invl[4];
  #pragma unroll
  for (int r=0;r<4;++r) invl[r] = 1.0f / lsum[r];
  #pragma unroll
  for (int j=0;j<4;++j)
    #pragma unroll
    for (int r=0;r<4;++r){
      int l = qr0 + quad*4 + r;
      if (l < LQ){
        float val = keepQ[r] > 0.5f ? Oacc[j][r] * invl[r] : vmv[j];
        Ob[((long)n*LQ + l)*DIM + h*64 + j*16 + col] = f2b(val);
      }
    }
}

// ---------------- host ----------------
extern "C" void kernel_launch(void* const* d_in, const int* in_sizes, int n_in,
                              void* d_out, int out_size, void* d_ws, size_t ws_size,
                              hipStream_t stream) {
  const float* patch    = (const float*)d_in[0];
  const int*   done     = (const int*)d_in[1];
  const float* W_embed  = (const float*)d_in[2];
  const float* b_embed  = (const float*)d_in[3];
  const float* spatial  = (const float*)d_in[4];
  const float* temporal = (const float*)d_in[5];
  const float* ln1_g    = (const float*)d_in[6];
  const float* ln1_b    = (const float*)d_in[7];
  const float* Wqkv     = (const float*)d_in[8];
  const float* bqkv     = (const float*)d_in[9];
  const float* Wo       = (const float*)d_in[10];
  const float* bo       = (const float*)d_in[11];
  const float* ln2_g    = (const float*)d_in[12];
  const float* ln2_b    = (const float*)d_in[13];
  const float* W1       = (const float*)d_in[14];
  const float* b1       = (const float*)d_in[15];
  const float* W2       = (const float*)d_in[16];
  const float* b2       = (const float*)d_in[17];
  const float* out_g    = (const float*)d_in[18];
  const float* out_b    = (const float*)d_in[19];
  float* out = (float*)d_out;

  char* ws = (char*)d_ws;
  size_t off = 0;
  auto alloc = [&](size_t bytes)->char*{ char* p = ws + off; off += (bytes + 255) & ~(size_t)255; return p; };
  const size_t QKV_B = (size_t)NB*HEADS*LQP*64*2;
  float* x    = (float*)alloc((size_t)MROWS*DIM*4);
  short* hbuf = (short*)alloc((size_t)MROWS*DIM*2);
  char*  U    = alloc((size_t)MROWS*MLP*2);
  short* patchb = (short*)U;
  short* Qb   = (short*)U;
  short* Kbf  = (short*)(U + QKV_B);
  short* Vtb  = (short*)(U + 2*QKV_B);
  short* obuf = hbuf;
  short* mid  = (short*)U;
  short* Wembt = (short*)alloc((size_t)512*448*2);
  short* Wqkvt = (short*)alloc((size_t)4*1536*512*2);
  short* Wot   = (short*)alloc((size_t)4*512*512*2);
  short* W1t   = (short*)alloc((size_t)4*2048*512*2);
  short* W2t   = (short*)alloc((size_t)4*512*2048*2);
  float* keepL = (float*)alloc((size_t)NB*LQP*4);
  int*   kmask = (int*)alloc(NB*4);
  int*   liveg = (int*)alloc(392*4);
  float* Vm    = (float*)alloc((size_t)NB*HEADS*64*4);

  mask_k<<<1, 512, 0, stream>>>(done, keepL, kmask, liveg);
  prep_k<<<PB0+PB1+PB2+PB3+PB4+PB5, 256, 0, stream>>>(
      patch, patchb, W_embed, Wembt, Wqkv, Wqkvt, Wo, Wot, W1, W1t, W2, W2t);

  gemm_k<0><<<dim3(DIM/128, MROWS/128), 256, 0, stream>>>(
      patchb, Wembt, b_embed, KPAD, DIM, x, nullptr, spatial, temporal,
      nullptr, nullptr, nullptr, nullptr);

  zpad_k<<<1152, 256, 0, stream>>>(Qb, Kbf, Vtb);

  for (int i = 0; i < 4; ++i){
    ln_k<<<MROWS/4, 256, 0, stream>>>(x, ln1_g + i*DIM, ln1_b + i*DIM, hbuf, nullptr);
    gemm_k<1><<<dim3(1536/128, MROWS/128), 256, 0, stream>>>(
        hbuf, Wqkvt + (size_t)i*1536*512, bqkv + (size_t)i*1536, DIM, 1536,
        nullptr, nullptr, nullptr, nullptr, Qb, Kbf, Vtb, liveg);
    vmean_k<<<NB*HEADS, 256, 0, stream>>>(Vtb, Vm);
    attn_k<<<dim3(13, HEADS, NB), 256, 0, stream>>>(Qb, Kbf, Vtb, keepL, kmask, Vm, obuf);
    gemm_k<2><<<dim3(DIM/128, MROWS/128), 256, 0, stream>>>(
        obuf, Wot + (size_t)i*512*512, bo + (size_t)i*DIM, DIM, DIM,
        x, nullptr, nullptr, nullptr, nullptr, nullptr, nullptr, nullptr);
    ln_k<<<MROWS/4, 256, 0, stream>>>(x, ln2_g + i*DIM, ln2_b + i*DIM, hbuf, nullptr);
    gemm_k<3><<<dim3(MLP/128, MROWS/128), 256, 0, stream>>>(
        hbuf, W1t + (size_t)i*2048*512, b1 + (size_t)i*MLP, DIM, MLP,
        nullptr, mid, nullptr, nullptr, nullptr, nullptr, nullptr, nullptr);
    gemm_k<2><<<dim3(DIM/128, MROWS/128), 256, 0, stream>>>(
        mid, W2t + (size_t)i*512*2048, b2 + (size_t)i*DIM, MLP, DIM,
        x, nullptr, nullptr, nullptr, nullptr, nullptr, nullptr, nullptr);
  }
  ln_k<<<MROWS/4, 256, 0, stream>>>(x, out_g, out_b, nullptr, out);
}

// Round 6
// 1548.057 us; speedup vs baseline: 1.2311x; 1.1257x over previous
//
#include <hip/hip_runtime.h>
#include <math.h>

#define NB 32
#define LQ 784
#define LQP 832   // 13*64, padded sequence length for attention buffers
#define DIM 512
#define HEADS 8
#define MLP 2048
#define KPAD 448
#define MROWS 25088  // NB*LQ

typedef __attribute__((ext_vector_type(8))) short s8v;
typedef __attribute__((ext_vector_type(4))) short s4v;
typedef __attribute__((ext_vector_type(4))) float f4v;

__device__ __forceinline__ short f2b(float f){
  unsigned u = __builtin_bit_cast(unsigned, f);
  u = (u + 0x7fffu + ((u >> 16) & 1u)) >> 16;
  return (short)u;
}
__device__ __forceinline__ float b2f(short s){
  unsigned u = ((unsigned)(unsigned short)s) << 16;
  return __builtin_bit_cast(float, u);
}

// async global->LDS, 16B per lane. LDS dest pattern must be wave-uniform base + lane*16.
__device__ __forceinline__ void gll16(const short* g, short* l){
  __builtin_amdgcn_global_load_lds(
      (const __attribute__((address_space(1))) void*)g,
      (__attribute__((address_space(3))) void*)l, 16, 0, 0);
}

// T1: bijective XCD-aware remap (m204). Consecutive flat ids round-robin over
// 8 XCDs; remap so each XCD owns a CONTIGUOUS chunk of tiles (contiguous bm
// rows x all bn) -> A-panels + B stay L2-resident per XCD instead of being
// replicated into all 8 L2s and served from L3.
__device__ __forceinline__ void xcd_remap(int &bm, int &bn, int gx, int gy){
  int nwg = gx * gy;
  int flat = bm * gx + bn;
  int xcd = flat & 7, idx = flat >> 3;
  int q = nwg >> 3, r = nwg & 7;
  int nf = (xcd < r ? xcd * (q + 1) : r * (q + 1) + (xcd - r) * q) + idx;
  bm = nf / gx;
  bn = nf - bm * gx;
}

// ---------------- fused mask prep (single block) ----------------
__global__ __launch_bounds__(512) void mask_k(const int* __restrict__ done, float* __restrict__ keepL,
                                              int* __restrict__ kmask, int* __restrict__ liveg){
  __shared__ float keep[32][16];
  int tid = threadIdx.x;
  { int n = tid >> 4, t = tid & 15;
    int any = 0;
    for (int c = t; c < 15; ++c) any |= done[n*15 + c];
    keep[n][t] = any ? 0.f : 1.f; }
  __syncthreads();
  for (int i = tid; i < NB*LQP; i += 512){
    int n = i / LQP, l = i - n*LQP;
    keepL[i] = (l < LQ) ? keep[n][l/49] : 0.f;
  }
  if (tid < 32){
    int n = tid, m = 0;
    for (int kb = 0; kb < 13; ++kb){
      int t0 = (kb*64)/49, t1 = (kb*64 + 63)/49; if (t1 > 15) t1 = 15;
      float a = 0.f;
      for (int t = t0; t <= t1; ++t) a += keep[n][t];
      if (a > 0.5f) m |= 1 << kb;
    }
    kmask[n] = m;
  }
  for (int g = tid; g < 392; g += 512){
    float a = 0.f;
    for (int i2 = 0; i2 < 64; ++i2){
      int row = g*64 + i2;
      int n = row / 784, l = row - n*784;
      a += keep[n][l/49];
    }
    liveg[g] = a > 0.5f ? 1 : 0;
  }
}

// zero pad rows/cols once, vectorized s8v stores
__global__ __launch_bounds__(256) void zpad_k(short* __restrict__ Qb, short* __restrict__ Kb,
                                              short* __restrict__ Vtb){
  int idx = blockIdx.x*256 + threadIdx.x;   // < 294912
  s8v z;
  #pragma unroll
  for (int e=0;e<8;++e) z[e] = 0;
  if (idx < 98304){
    int nh = idx / 384, r = idx - nh*384;
    *(s8v*)(Qb + (long)nh*LQP*64 + 784*64 + r*8) = z;
  } else if (idx < 196608){
    int i2 = idx - 98304; int nh = i2 / 384, r = i2 - nh*384;
    *(s8v*)(Kb + (long)nh*LQP*64 + 784*64 + r*8) = z;
  } else {
    int i2 = idx - 196608; int nh = i2 / 384, rem = i2 - nh*384, d = rem/6, s = rem - d*6;
    *(s8v*)(Vtb + ((long)nh*64 + d)*LQP + 784 + s*8) = z;
  }
}

// Vm[nh*64+d] = mean over l<784 of V  (V^T layout)
__global__ __launch_bounds__(256) void vmean_k(const short* __restrict__ Vtb, float* __restrict__ Vm){
  int nh = blockIdx.x;
  int tid = threadIdx.x;
  int d = tid >> 2, seg = tid & 3;
  const short* row = Vtb + ((long)nh*64 + d)*LQP;
  float s = 0.f;
  for (int c = seg; c < 98; c += 4){
    s8v v = *(const s8v*)(row + c*8);
    #pragma unroll
    for (int e=0;e<8;++e) s += b2f(v[e]);
  }
  s += __shfl_xor(s, 1, 64);
  s += __shfl_xor(s, 2, 64);
  if (seg == 0) Vm[nh*64 + d] = s * (1.0f/784.0f);
}

// ---------------- fused prep: patch pad+cast, 5 weight transposes, one launch ----------------
__device__ __forceinline__ void transp_body(long idx, const float* __restrict__ src,
                                            short* __restrict__ dst, int R, int C, int Rpad,
                                            long sStride, long dStride){
  long per = (long)C * Rpad;
  int z = (int)(idx / per);
  long rem = idx - (long)z * per;
  int cc = (int)(rem / Rpad);
  int r  = (int)(rem - (long)cc * Rpad);
  short v = 0;
  if (r < R) v = f2b(src[(long)z * sStride + (long)r * C + cc]);
  dst[(long)z * dStride + rem] = v;
}

#define PB0 43904   // padpatch
#define PB1 896     // Wemb
#define PB2 12288   // Wqkv
#define PB3 4096    // Wo
#define PB4 16384   // W1
#define PB5 16384   // W2

__global__ __launch_bounds__(256) void prep_k(
    const float* __restrict__ patch, short* __restrict__ patchb,
    const float* __restrict__ Wemb, short* __restrict__ Wembt,
    const float* __restrict__ Wqkv, short* __restrict__ Wqkvt,
    const float* __restrict__ Wo, short* __restrict__ Wot,
    const float* __restrict__ W1, short* __restrict__ W1t,
    const float* __restrict__ W2, short* __restrict__ W2t){
  int b = blockIdx.x;
  int tid = threadIdx.x;
  if (b < PB0){
    long idx = (long)b*256 + tid;
    if (idx >= (long)MROWS*KPAD) return;
    int r = (int)(idx / KPAD);
    int c = (int)(idx - (long)r*KPAD);
    patchb[idx] = (c < 432) ? f2b(patch[(long)r*432 + c]) : (short)0;
  } else if (b < PB0+PB1){
    long idx = (long)(b-PB0)*256 + tid;
    if (idx < 229376) transp_body(idx, Wemb, Wembt, 432, 512, 448, 0, 0);
  } else if (b < PB0+PB1+PB2){
    long idx = (long)(b-PB0-PB1)*256 + tid;
    if (idx < 3145728) transp_body(idx, Wqkv, Wqkvt, 512, 1536, 512, 512L*1536, 1536L*512);
  } else if (b < PB0+PB1+PB2+PB3){
    long idx = (long)(b-PB0-PB1-PB2)*256 + tid;
    if (idx < 1048576) transp_body(idx, Wo, Wot, 512, 512, 512, 512L*512, 512L*512);
  } else if (b < PB0+PB1+PB2+PB3+PB4){
    long idx = (long)(b-PB0-PB1-PB2-PB3)*256 + tid;
    if (idx < 4194304) transp_body(idx, W1, W1t, 512, 2048, 512, 512L*2048, 2048L*512);
  } else {
    long idx = (long)(b-PB0-PB1-PB2-PB3-PB4)*256 + tid;
    if (idx < 4194304) transp_body(idx, W2, W2t, 2048, 512, 2048, 2048L*512, 512L*2048);
  }
}

// ---------------- layernorm: 1 wave per 512-wide row, 4 rows/block ----------------
__global__ __launch_bounds__(256) void ln_k(const float* __restrict__ x, const float* __restrict__ g,
                                            const float* __restrict__ b, short* __restrict__ outb,
                                            float* __restrict__ outf){
  int lane = threadIdx.x & 63;
  long row = (long)blockIdx.x * 4 + (threadIdx.x >> 6);
  const float* xr = x + row * DIM + lane * 8;
  float va[8];
  { float4 t0 = *(const float4*)xr; float4 t1 = *(const float4*)(xr + 4);
    va[0]=t0.x; va[1]=t0.y; va[2]=t0.z; va[3]=t0.w;
    va[4]=t1.x; va[5]=t1.y; va[6]=t1.z; va[7]=t1.w; }
  float s = 0.f, q = 0.f;
  #pragma unroll
  for (int j=0;j<8;++j){ s += va[j]; q += va[j]*va[j]; }
  #pragma unroll
  for (int m=1;m<64;m<<=1){ s += __shfl_xor(s,m,64); q += __shfl_xor(q,m,64); }
  float mean = s * (1.0f/DIM);
  float var = q * (1.0f/DIM) - mean*mean;
  float inv = rsqrtf(var + 1e-5f);
  int cb = lane*8;
  if (outb){
    s8v o;
    #pragma unroll
    for (int j=0;j<8;++j) o[j] = f2b((va[j]-mean)*inv*g[cb+j] + b[cb+j]);
    *(s8v*)(outb + row*DIM + cb) = o;
  } else {
    float4 t0, t1;
    t0.x=(va[0]-mean)*inv*g[cb+0]+b[cb+0]; t0.y=(va[1]-mean)*inv*g[cb+1]+b[cb+1];
    t0.z=(va[2]-mean)*inv*g[cb+2]+b[cb+2]; t0.w=(va[3]-mean)*inv*g[cb+3]+b[cb+3];
    t1.x=(va[4]-mean)*inv*g[cb+4]+b[cb+4]; t1.y=(va[5]-mean)*inv*g[cb+5]+b[cb+5];
    t1.z=(va[6]-mean)*inv*g[cb+6]+b[cb+6]; t1.w=(va[7]-mean)*inv*g[cb+7]+b[cb+7];
    *(float4*)(outf + row*DIM + cb) = t0;
    *(float4*)(outf + row*DIM + cb + 4) = t1;
  }
}

// ---------------- GEMM with operand-swapped MFMA (acc = C^T) ----------------
// Round-2 schedule (proven best): 2-phase double-buffered, counted vmcnt:
//   s_barrier; stage(t+1); s_waitcnt vmcnt(8); s_barrier; MFMA(buf[t])
// + T1 XCD remap for L2 locality of A-panels.
template<int EPI>
__global__ __launch_bounds__(256) void gemm_k(
    const short* __restrict__ A, const short* __restrict__ Bt,
    const float* __restrict__ bias, int K, int N,
    float* __restrict__ xres, short* __restrict__ outb,
    const float* __restrict__ sp, const float* __restrict__ tp,
    short* __restrict__ Qb, short* __restrict__ Kb, short* __restrict__ Vtb,
    const int* __restrict__ liveg)
{
  __shared__ __align__(16) short lA[2][128*64];
  __shared__ __align__(16) short lB[2][128*64];
  int bm = blockIdx.y, bn = blockIdx.x;
  xcd_remap(bm, bn, gridDim.x, gridDim.y);
  if (EPI == 1){
    if (bn < 8 && liveg[2*bm] == 0 && liveg[2*bm+1] == 0) return;
  }
  int tid = threadIdx.x;
  int lane = tid & 63, wid = tid >> 6;
  int col = lane & 15, quad = lane >> 4;
  int wm = (wid >> 1) * 64, wn = (wid & 1) * 64;
  f4v acc[4][4];   // acc[i][j]: cols wn+i*16+quad*4+(0..3), row wm+j*16+col
  #pragma unroll
  for (int i=0;i<4;++i)
    #pragma unroll
    for (int j=0;j<4;++j)
      #pragma unroll
      for (int e=0;e<4;++e) acc[i][j][e] = 0.0f;
  const short* Abase = A + (long)bm*128*K;
  const short* Bbase = Bt + (long)bn*128*K;
  int nt = K >> 6;
  // prologue: stage K-tile 0 into buffer 0 (stays in flight into the loop)
  #pragma unroll
  for (int c = 0; c < 4; ++c){
    int v = c*256 + tid;
    int r = v >> 3, j = v & 7;
    int kc = (j ^ (r & 7)) * 8;
    gll16(Abase + (long)r*K + kc, lA[0] + v*8);
    gll16(Bbase + (long)r*K + kc, lB[0] + v*8);
  }
  for (int t = 0; t < nt; ++t){
    int cur = t & 1;
    __builtin_amdgcn_s_barrier();              // buf[cur^1] free (read finished in t-1)
    __builtin_amdgcn_sched_barrier(0);
    if (t + 1 < nt){
      int kt = (t + 1) << 6;
      #pragma unroll
      for (int c = 0; c < 4; ++c){
        int v = c*256 + tid;
        int r = v >> 3, j = v & 7;
        int kc = (j ^ (r & 7)) * 8;
        gll16(Abase + (long)r*K + kt + kc, lA[cur^1] + v*8);
        gll16(Bbase + (long)r*K + kt + kc, lB[cur^1] + v*8);
      }
      asm volatile("s_waitcnt vmcnt(8)" ::: "memory");   // stage(t) done; t+1 in flight
    } else {
      asm volatile("s_waitcnt vmcnt(0)" ::: "memory");   // last tile: drain
    }
    __builtin_amdgcn_s_barrier();              // stage(t) visible to all waves
    __builtin_amdgcn_sched_barrier(0);
    __builtin_amdgcn_s_setprio(1);
    #pragma unroll
    for (int ks = 0; ks < 2; ++ks){
      s8v af[4], bf[4];
      #pragma unroll
      for (int j=0;j<4;++j)
        af[j] = *(const s8v*)&lA[cur][(wm + j*16 + col)*64 + (((ks*4+quad) ^ (col&7)))*8];
      #pragma unroll
      for (int i=0;i<4;++i)
        bf[i] = *(const s8v*)&lB[cur][(wn + i*16 + col)*64 + (((ks*4+quad) ^ (col&7)))*8];
      #pragma unroll
      for (int i=0;i<4;++i)
        #pragma unroll
        for (int j=0;j<4;++j)
          acc[i][j] = __builtin_amdgcn_mfma_f32_16x16x32_bf16(bf[i], af[j], acc[i][j], 0, 0, 0);
    }
    __builtin_amdgcn_s_setprio(0);
    __builtin_amdgcn_sched_barrier(0);
  }
  #pragma unroll
  for (int j=0;j<4;++j){
    int grow = (int)bm*128 + wm + j*16 + col;
    int l = 0, t = 0, p = 0, n = 0;
    if (EPI == 0){ l = grow % LQ; t = l / 49; p = l - t*49; }
    if (EPI == 1){ n = grow / LQ; l = grow - n*LQ; }
    #pragma unroll
    for (int i=0;i<4;++i){
      int gc0 = (int)bn*128 + wn + i*16 + quad*4;
      float4 b4 = *(const float4*)(bias + gc0);
      float v0 = acc[i][j][0] + b4.x;
      float v1 = acc[i][j][1] + b4.y;
      float v2 = acc[i][j][2] + b4.z;
      float v3 = acc[i][j][3] + b4.w;
      if (EPI == 0){
        float4 s4 = *(const float4*)(sp + p*DIM + gc0);
        float4 t4 = *(const float4*)(tp + t*DIM + gc0);
        float4 o; o.x = v0 + s4.x + t4.x; o.y = v1 + s4.y + t4.y;
        o.z = v2 + s4.z + t4.z; o.w = v3 + s4.w + t4.w;
        *(float4*)(xres + (long)grow*DIM + gc0) = o;
      } else if (EPI == 1){
        if (gc0 < 512){
          int hh = gc0 >> 6, d0 = gc0 & 63;
          s4v o; o[0]=f2b(v0); o[1]=f2b(v1); o[2]=f2b(v2); o[3]=f2b(v3);
          *(s4v*)(Qb + (((long)(n*HEADS + hh))*LQP + l)*64 + d0) = o;
        } else if (gc0 < 1024){
          int c2 = gc0 - 512; int hh = c2 >> 6, d0 = c2 & 63;
          s4v o; o[0]=f2b(v0); o[1]=f2b(v1); o[2]=f2b(v2); o[3]=f2b(v3);
          *(s4v*)(Kb + (((long)(n*HEADS + hh))*LQP + l)*64 + d0) = o;
        } else {
          int c2 = gc0 - 1024; int hh = c2 >> 6, d0 = c2 & 63;
          long base = ((long)(n*HEADS + hh))*64;
          Vtb[(base + d0+0)*LQP + l] = f2b(v0);
          Vtb[(base + d0+1)*LQP + l] = f2b(v1);
          Vtb[(base + d0+2)*LQP + l] = f2b(v2);
          Vtb[(base + d0+3)*LQP + l] = f2b(v3);
        }
      } else if (EPI == 2){
        float4 xo = *(const float4*)(xres + (long)grow*DIM + gc0);
        xo.x += v0; xo.y += v1; xo.z += v2; xo.w += v3;
        *(float4*)(xres + (long)grow*DIM + gc0) = xo;
      } else if (EPI == 3){
        float g0 = v0 / (1.0f + __expf(-1.595769122f * v0 * (1.0f + 0.044715f*v0*v0)));
        float g1 = v1 / (1.0f + __expf(-1.595769122f * v1 * (1.0f + 0.044715f*v1*v1)));
        float g2 = v2 / (1.0f + __expf(-1.595769122f * v2 * (1.0f + 0.044715f*v2*v2)));
        float g3 = v3 / (1.0f + __expf(-1.595769122f * v3 * (1.0f + 0.044715f*v3*v3)));
        s4v o; o[0]=f2b(g0); o[1]=f2b(g1); o[2]=f2b(g2); o[3]=f2b(g3);
        *(s4v*)(outb + (long)grow*MLP + gc0) = o;
      }
    }
  }
}

// ---------------- sparse flash attention (unchanged) ----------------
__global__ __launch_bounds__(256) void attn_k(
    const short* __restrict__ Qb, const short* __restrict__ Kb,
    const short* __restrict__ Vtb, const float* __restrict__ keepL,
    const int* __restrict__ kmask, const float* __restrict__ Vm,
    short* __restrict__ Ob)
{
  __shared__ __align__(16) short lK[64*64];
  __shared__ __align__(16) short lV[64*64];
  __shared__ __align__(16) short lP[4][16*72];
  int tid = threadIdx.x;
  int lane = tid & 63, wid = tid >> 6;
  int col = lane & 15, quad = lane >> 4;
  int qb = blockIdx.x, h = blockIdx.y, n = blockIdx.z;
  long nh = (long)n*HEADS + h;
  int smask = kmask[n];
  int qr0 = qb*64 + wid*16;
  float vmv[4];
  #pragma unroll
  for (int j=0;j<4;++j) vmv[j] = Vm[nh*64 + j*16 + col];

  if (!((smask >> qb) & 1)){
    #pragma unroll
    for (int j=0;j<4;++j){
      short ov = f2b(vmv[j]);
      #pragma unroll
      for (int r=0;r<4;++r){
        int l = qr0 + quad*4 + r;
        if (l < LQ) Ob[((long)n*LQ + l)*DIM + h*64 + j*16 + col] = ov;
      }
    }
    return;
  }

  const float* kl = keepL + n*LQP;
  const short* qp = Qb + (nh*LQP + qr0 + col)*64 + quad*8;
  s8v aq0 = *(const s8v*)qp;
  s8v aq1 = *(const s8v*)(qp + 32);
  float keepA = kl[qr0 + col];
  if (keepA < 0.5f){
    #pragma unroll
    for (int e=0;e<8;++e){ aq0[e] = 0; aq1[e] = 0; }
  }
  float keepQ[4];
  #pragma unroll
  for (int r=0;r<4;++r) keepQ[r] = kl[qr0 + quad*4 + r];
  float kqs = keepQ[0] + keepQ[1] + keepQ[2] + keepQ[3];
  bool wlive = __ballot(kqs > 0.5f) != 0ull;
  float lsum[4] = {0.f,0.f,0.f,0.f};
  f4v Oacc[4];
  #pragma unroll
  for (int j=0;j<4;++j)
    #pragma unroll
    for (int e=0;e<4;++e) Oacc[j][e] = 0.0f;

  for (int kb = 0; kb < 13; ++kb){
    if (!((smask >> kb) & 1)) continue;
    int kbase = kb*64;
    __syncthreads();
    #pragma unroll
    for (int c = 0; c < 2; ++c){
      int v = c*256 + tid;
      int r = v >> 3, j = v & 7;
      int kc = (j ^ (r & 7)) * 8;
      gll16(Kb + (nh*LQP + kbase + r)*64 + kc, lK + v*8);
    }
    #pragma unroll
    for (int c = 0; c < 2; ++c){
      int v = c*256 + tid;
      int d = v >> 3, j = v & 7;
      int c8 = (j ^ (d & 7)) * 8;
      gll16(Vtb + (nh*64 + d)*LQP + kbase + c8, lV + v*8);
    }
    __syncthreads();
    if (!wlive) continue;
    float pm[4][4];
    #pragma unroll
    for (int ct = 0; ct < 4; ++ct){
      float keepK = kl[kbase + ct*16 + col];
      f4v s;
      #pragma unroll
      for (int e=0;e<4;++e) s[e] = 0.0f;
      #pragma unroll
      for (int ks = 0; ks < 2; ++ks){
        s8v bk = *(const s8v*)&lK[(ct*16 + col)*64 + (((ks*4+quad) ^ (col&7)))*8];
        if (keepK < 0.5f){
          #pragma unroll
          for (int e=0;e<8;++e) bk[e] = 0;
        }
        s = __builtin_amdgcn_mfma_f32_16x16x32_bf16(ks ? aq1 : aq0, bk, s, 0, 0, 0);
      }
      #pragma unroll
      for (int r=0;r<4;++r){
        float a = keepQ[r] * keepK;
        float t = fmaf(s[r], 0.125f, 10000.0f);
        float p = __expf(fmaf(a, t, -10000.0f));
        pm[ct][r] = p;
        lsum[r] += p;
      }
    }
    #pragma unroll
    for (int ct=0; ct<4; ++ct)
      #pragma unroll
      for (int r=0;r<4;++r)
        lP[wid][(quad*4 + r)*72 + ct*16 + col] = f2b(pm[ct][r]);
    #pragma unroll
    for (int j=0;j<4;++j){
      #pragma unroll
      for (int ks=0; ks<2; ++ks){
        s8v ap = *(const s8v*)&lP[wid][col*72 + ks*32 + quad*8];
        s8v bv = *(const s8v*)&lV[(j*16 + col)*64 + (((ks*4+quad) ^ (col&7)))*8];
        Oacc[j] = __builtin_amdgcn_mfma_f32_16x16x32_bf16(ap, bv, Oacc[j], 0, 0, 0);
      }
    }
  }
  #pragma unroll
  for (int m=1; m<16; m<<=1){
    #pragma unroll
    for (int r=0;r<4;++r) lsum[r] += __shfl_xor(lsum[r], m, 64);
  }
  float invl[4];
  #pragma unroll
  for (int r=0;r<4;++r) invl[r] = 1.0f / lsum[r];
  #pragma unroll
  for (int j=0;j<4;++j)
    #pragma unroll
    for (int r=0;r<4;++r){
      int l = qr0 + quad*4 + r;
      if (l < LQ){
        float val = keepQ[r] > 0.5f ? Oacc[j][r] * invl[r] : vmv[j];
        Ob[((long)n*LQ + l)*DIM + h*64 + j*16 + col] = f2b(val);
      }
    }
}

// ---------------- host ----------------
extern "C" void kernel_launch(void* const* d_in, const int* in_sizes, int n_in,
                              void* d_out, int out_size, void* d_ws, size_t ws_size,
                              hipStream_t stream) {
  const float* patch    = (const float*)d_in[0];
  const int*   done     = (const int*)d_in[1];
  const float* W_embed  = (const float*)d_in[2];
  const float* b_embed  = (const float*)d_in[3];
  const float* spatial  = (const float*)d_in[4];
  const float* temporal = (const float*)d_in[5];
  const float* ln1_g    = (const float*)d_in[6];
  const float* ln1_b    = (const float*)d_in[7];
  const float* Wqkv     = (const float*)d_in[8];
  const float* bqkv     = (const float*)d_in[9];
  const float* Wo       = (const float*)d_in[10];
  const float* bo       = (const float*)d_in[11];
  const float* ln2_g    = (const float*)d_in[12];
  const float* ln2_b    = (const float*)d_in[13];
  const float* W1       = (const float*)d_in[14];
  const float* b1       = (const float*)d_in[15];
  const float* W2       = (const float*)d_in[16];
  const float* b2       = (const float*)d_in[17];
  const float* out_g    = (const float*)d_in[18];
  const float* out_b    = (const float*)d_in[19];
  float* out = (float*)d_out;

  char* ws = (char*)d_ws;
  size_t off = 0;
  auto alloc = [&](size_t bytes)->char*{ char* p = ws + off; off += (bytes + 255) & ~(size_t)255; return p; };
  const size_t QKV_B = (size_t)NB*HEADS*LQP*64*2;
  float* x    = (float*)alloc((size_t)MROWS*DIM*4);
  short* hbuf = (short*)alloc((size_t)MROWS*DIM*2);
  char*  U    = alloc((size_t)MROWS*MLP*2);
  short* patchb = (short*)U;
  short* Qb   = (short*)U;
  short* Kbf  = (short*)(U + QKV_B);
  short* Vtb  = (short*)(U + 2*QKV_B);
  short* obuf = hbuf;
  short* mid  = (short*)U;
  short* Wembt = (short*)alloc((size_t)512*448*2);
  short* Wqkvt = (short*)alloc((size_t)4*1536*512*2);
  short* Wot   = (short*)alloc((size_t)4*512*512*2);
  short* W1t   = (short*)alloc((size_t)4*2048*512*2);
  short* W2t   = (short*)alloc((size_t)4*512*2048*2);
  float* keepL = (float*)alloc((size_t)NB*LQP*4);
  int*   kmask = (int*)alloc(NB*4);
  int*   liveg = (int*)alloc(392*4);
  float* Vm    = (float*)alloc((size_t)NB*HEADS*64*4);

  mask_k<<<1, 512, 0, stream>>>(done, keepL, kmask, liveg);
  prep_k<<<PB0+PB1+PB2+PB3+PB4+PB5, 256, 0, stream>>>(
      patch, patchb, W_embed, Wembt, Wqkv, Wqkvt, Wo, Wot, W1, W1t, W2, W2t);

  gemm_k<0><<<dim3(DIM/128, MROWS/128), 256, 0, stream>>>(
      patchb, Wembt, b_embed, KPAD, DIM, x, nullptr, spatial, temporal,
      nullptr, nullptr, nullptr, nullptr);

  zpad_k<<<1152, 256, 0, stream>>>(Qb, Kbf, Vtb);

  for (int i = 0; i < 4; ++i){
    ln_k<<<MROWS/4, 256, 0, stream>>>(x, ln1_g + i*DIM, ln1_b + i*DIM, hbuf, nullptr);
    gemm_k<1><<<dim3(1536/128, MROWS/128), 256, 0, stream>>>(
        hbuf, Wqkvt + (size_t)i*1536*512, bqkv + (size_t)i*1536, DIM, 1536,
        nullptr, nullptr, nullptr, nullptr, Qb, Kbf, Vtb, liveg);
    vmean_k<<<NB*HEADS, 256, 0, stream>>>(Vtb, Vm);
    attn_k<<<dim3(13, HEADS, NB), 256, 0, stream>>>(Qb, Kbf, Vtb, keepL, kmask, Vm, obuf);
    gemm_k<2><<<dim3(DIM/128, MROWS/128), 256, 0, stream>>>(
        obuf, Wot + (size_t)i*512*512, bo + (size_t)i*DIM, DIM, DIM,
        x, nullptr, nullptr, nullptr, nullptr, nullptr, nullptr, nullptr);
    ln_k<<<MROWS/4, 256, 0, stream>>>(x, ln2_g + i*DIM, ln2_b + i*DIM, hbuf, nullptr);
    gemm_k<3><<<dim3(MLP/128, MROWS/128), 256, 0, stream>>>(
        hbuf, W1t + (size_t)i*2048*512, b1 + (size_t)i*MLP, DIM, MLP,
        nullptr, mid, nullptr, nullptr, nullptr, nullptr, nullptr, nullptr);
    gemm_k<2><<<dim3(DIM/128, MROWS/128), 256, 0, stream>>>(
        mid, W2t + (size_t)i*512*2048, b2 + (size_t)i*DIM, MLP, DIM,
        x, nullptr, nullptr, nullptr, nullptr, nullptr, nullptr, nullptr);
  }
  ln_k<<<MROWS/4, 256, 0, stream>>>(x, out_g, out_b, nullptr, out);
}